// Round 3
// baseline (933.418 us; speedup 1.0000x reference)
//
#include <hip/hip_runtime.h>

#define BB 16
#define NN 50
#define HH 128
#define VV 40000
#define VO 39999

// ---- workspace layout (float offsets) ---- total 411,664 floats = 1.65 MB
#define OFF_HID    0          // 800*128
#define OFF_EIN    102400     // 800*128
#define OFF_EOUT   204800     // 800*128
#define OFF_QT     307200     // 800*128
#define OFF_AF     409600     // 16*128
#define OFF_LEN    411648     // 16 ints

__device__ __forceinline__ float sigm(float x){ return 1.0f/(1.0f+__expf(-x)); }

// ---- hidden = emb[items]  (800*128) ----
__global__ void k_embed(const int* __restrict__ items, const float* __restrict__ emb,
                        float* __restrict__ ws){
  int idx = blockIdx.x*256 + threadIdx.x;   // grid covers exactly 102400
  int r = idx >> 7, h = idx & 127;
  ws[OFF_HID + idx] = emb[items[r]*128 + h];
}

// ---- ein/eout = hidden @ W^T + b   (8 rows per block) ----
__global__ void k_einout(const float* __restrict__ W_ein, const float* __restrict__ b_ein,
                         const float* __restrict__ W_eout, const float* __restrict__ b_eout,
                         float* __restrict__ ws){
  __shared__ float hl[1024];
  int t = threadIdx.x;
  int r0 = blockIdx.x * 8;
  for (int i=0;i<4;i++) hl[t + i*256] = ws[OFF_HID + r0*128 + t + i*256];
  __syncthreads();
  int h = t & 127;
  const float* W = (t<128) ? W_ein : W_eout;
  float bias = ((t<128)? b_ein : b_eout)[h];
  float* dst = (t<128) ? (ws+OFF_EIN) : (ws+OFF_EOUT);
  // preload W row h (contiguous 128 f32) into registers
  float wr[128];
  const float4* wp = (const float4*)(W + h*128);
  #pragma unroll
  for (int q=0;q<32;q++){
    float4 w = wp[q];
    wr[q*4]=w.x; wr[q*4+1]=w.y; wr[q*4+2]=w.z; wr[q*4+3]=w.w;
  }
  for (int rr=0; rr<8; rr++){
    float acc = bias;
    const float* hr = hl + rr*128;
    #pragma unroll 8
    for (int k=0;k<128;k++) acc += hr[k] * wr[k];
    dst[(r0+rr)*128 + h] = acc;
  }
}

// ---- fused: A-propagation + GRU gates + hidden update (8 rows of one batch per block) ----
__global__ void k_cell(const float* __restrict__ A, const float* __restrict__ b_iah,
                       const float* __restrict__ b_oah, const float* __restrict__ w_ih,
                       const float* __restrict__ w_hh, const float* __restrict__ b_ih,
                       const float* __restrict__ b_hh, float* __restrict__ ws){
  __shared__ float inp[8*256];
  __shared__ float hl[8*128];
  __shared__ float gil[8*384];
  __shared__ float ghl[8*384];
  int t = threadIdx.x;
  int b = blockIdx.x / 7;
  int n0 = (blockIdx.x - b*7) * 8;
  const float* ein  = ws + OFF_EIN  + b*NN*128;
  const float* eout = ws + OFF_EOUT + b*NN*128;
  // stage hidden rows
  for (int i=0;i<4;i++){
    int o = t + i*256; int rr = o>>7, h = o&127;
    int row = n0 + rr;
    hl[o] = (row < NN) ? ws[OFF_HID + (b*NN+row)*128 + h] : 0.0f;
  }
  // phase 1: input_in/input_out -> inp[rr*256 + c]
  int c = t & 127;
  int half = (t < 128);
  float bias1 = (half? b_iah : b_oah)[c];
  const float* src = half ? ein : eout;
  for (int i=0;i<8;i++){
    int row = n0 + i;
    if (row < NN){
      float acc = bias1;
      const float* ar = A + (b*NN+row)*(2*NN) + (half?0:NN);
      for (int m=0;m<NN;m++) acc += ar[m] * src[m*128 + c];
      inp[i*256 + t] = acc;
    } else inp[i*256 + t] = 0.0f;
  }
  __syncthreads();
  // phase 2: gi = inp @ w_ih^T + b_ih ; gh = hidden @ w_hh^T + b_hh
  for (int i=0;i<12;i++){
    int o = t + i*256;
    int rr = o/384, j = o - rr*384;
    float gi = b_ih[j];
    float gh = b_hh[j];
    const float* ir = inp + rr*256;
    const float* hr = hl + rr*128;
    const float4* wi = (const float4*)(w_ih + j*256);
    const float4* wh = (const float4*)(w_hh + j*128);
    #pragma unroll 8
    for (int q=0;q<64;q++){
      float4 e = wi[q];
      const float* irq = ir + q*4;
      gi += irq[0]*e.x + irq[1]*e.y + irq[2]*e.z + irq[3]*e.w;
    }
    #pragma unroll 8
    for (int q=0;q<32;q++){
      float4 e = wh[q];
      const float* hrq = hr + q*4;
      gh += hrq[0]*e.x + hrq[1]*e.y + hrq[2]*e.z + hrq[3]*e.w;
    }
    gil[o] = gi; ghl[o] = gh;
  }
  __syncthreads();
  // phase 3: gates + update
  for (int i=0;i<4;i++){
    int o = t + i*256; int rr = o>>7, h = o&127;
    int row = n0 + rr;
    if (row < NN){
      float ir_ = gil[rr*384 + h], ii = gil[rr*384 + 128 + h], inw = gil[rr*384 + 256 + h];
      float hr_ = ghl[rr*384 + h], hi = ghl[rr*384 + 128 + h], hn = ghl[rr*384 + 256 + h];
      float rg = sigm(ir_ + hr_);
      float ig = sigm(ii + hi);
      float ng = tanhf(inw + rg*hn);
      float hv = hl[o];
      ws[OFF_HID + (b*NN+row)*128 + h] = ng + ig*(hv - ng);
    }
  }
}

// ---- attention readout: a_final (B,128) and lengths ----
__global__ void k_attn(const int* __restrict__ mask, const float* __restrict__ W_one,
                       const float* __restrict__ b_one, const float* __restrict__ W_two,
                       const float* __restrict__ b_two, const float* __restrict__ w_three,
                       const float* __restrict__ W_tr, const float* __restrict__ b_tr,
                       float* __restrict__ ws){
  __shared__ float htl[128], al[128], sg[NN];
  __shared__ float sgrid[NN][128];
  int t = threadIdx.x;       // block = 128
  int b = blockIdx.x;
  int len = 0;
  for (int n=0;n<NN;n++) len += mask[b*NN+n];
  if (len < 1) len = 1; if (len > NN) len = NN;
  const float* hid = ws + OFF_HID + b*NN*128;
  htl[t] = hid[(len-1)*128 + t];
  __syncthreads();
  float q1 = b_one[t];
  for (int k=0;k<128;k++) q1 += htl[k] * W_one[t*128+k];
  float w3 = w_three[t];
  float bt2 = b_two[t];
  for (int n=0;n<len;n++){
    float q2 = bt2;
    const float* hr = hid + n*128;
    for (int k=0;k<128;k++) q2 += hr[k] * W_two[t*128+k];
    sgrid[n][t] = w3 * sigm(q1 + q2);
  }
  __syncthreads();
  if (t < len){
    float s = 0;
    for (int h=0;h<128;h++) s += sgrid[t][h];
    sg[t] = s;
  }
  __syncthreads();
  if (t == 0){
    float m = -1e30f;
    for (int n=0;n<len;n++) m = fmaxf(m, sg[n]);
    float ssum = 0;
    for (int n=0;n<len;n++){ float e = __expf(sg[n]-m); sg[n] = e; ssum += e; }
    float inv = (ssum > 0.0f) ? 1.0f/ssum : 0.0f;
    for (int n=0;n<len;n++) sg[n] *= inv;
  }
  __syncthreads();
  float a = 0;
  for (int n=0;n<len;n++) a += sg[n] * hid[n*128 + t];
  al[t] = a;
  __syncthreads();
  float af = b_tr[t];
  for (int k=0;k<128;k++) af += al[k]  * W_tr[t*256 + k];
  for (int k=0;k<128;k++) af += htl[k] * W_tr[t*256 + 128 + k];
  ws[OFF_AF + b*128 + t] = af;
  if (t == 0) ((int*)(ws + OFF_LEN))[b] = len;
}

// ---- qt = (hidden * mask) @ W_t^T  (zero for masked rows) ----
__global__ void k_qt(const int* __restrict__ mask, const float* __restrict__ W_t,
                     float* __restrict__ ws){
  __shared__ float hl[1024];
  int t = threadIdx.x;
  int r0 = blockIdx.x * 8;
  for (int i=0;i<4;i++) hl[t+i*256] = ws[OFF_HID + r0*128 + t + i*256];
  __syncthreads();
  int h = t & 127;
  int rbase = t >> 7;   // 0 or 1
  float wr[128];
  const float4* wp = (const float4*)(W_t + h*128);
  #pragma unroll
  for (int q=0;q<32;q++){
    float4 w = wp[q];
    wr[q*4]=w.x; wr[q*4+1]=w.y; wr[q*4+2]=w.z; wr[q*4+3]=w.w;
  }
  for (int i=0;i<4;i++){
    int rr = rbase + i*2;
    int r = r0 + rr;
    float acc = 0.0f;
    if (mask[r]){
      const float* hr = hl + rr*128;
      #pragma unroll 8
      for (int k=0;k<128;k++) acc += hr[k]*wr[k];
    }
    ws[OFF_QT + r*128 + h] = acc;
  }
}

// ---- scores: per (v,b): l_n = emb_v . qt[b,n]; softmax over n<len; sum beta*l + a.emb ----
// identity: einsum(beta, qt*m) . emb_v == sum_n beta_n * (qt_n . emb_v) = sum_n beta_n * l_n
__global__ void __launch_bounds__(256) k_scores(const float* __restrict__ emb,
                                                const float* __restrict__ ws,
                                                float* __restrict__ out){
  int b = blockIdx.y;
  int v = blockIdx.x*256 + threadIdx.x;
  if (v >= VO) return;
  int len = ((const int*)(ws + OFF_LEN))[b];
  if (len < 1) len = 1; if (len > NN) len = NN;
  const float* erow = emb + (v+1)*128;
  const float* qtb = ws + OFF_QT + b*NN*128;
  const float* ab  = ws + OFF_AF + b*128;
  float l[NN];
  #pragma unroll
  for (int n=0;n<NN;n++) l[n] = 0.0f;
  float acc_a = 0.0f;
  #pragma unroll 1
  for (int cc=0; cc<4; cc++){
    int k0 = cc*32;
    float e[32];
    const float4* p = (const float4*)(erow + k0);
    #pragma unroll
    for (int q=0;q<8;q++){
      float4 w = p[q];
      e[q*4]=w.x; e[q*4+1]=w.y; e[q*4+2]=w.z; e[q*4+3]=w.w;
    }
    #pragma unroll
    for (int n=0;n<NN;n++){
      const float4* q4 = (const float4*)(qtb + n*128 + k0);  // thread-uniform
      float s = l[n];
      #pragma unroll
      for (int i=0;i<8;i++){
        float4 qv = q4[i];
        s += qv.x*e[i*4] + qv.y*e[i*4+1] + qv.z*e[i*4+2] + qv.w*e[i*4+3];
      }
      l[n] = s;
    }
    const float4* a4 = (const float4*)(ab + k0);
    #pragma unroll
    for (int i=0;i<8;i++){
      float4 av = a4[i];
      acc_a += av.x*e[i*4] + av.y*e[i*4+1] + av.z*e[i*4+2] + av.w*e[i*4+3];
    }
  }
  float m = -1e30f;
  #pragma unroll
  for (int n=0;n<NN;n++) if (n<len) m = fmaxf(m, l[n]);
  float ssum = 0.0f, num = 0.0f;
  #pragma unroll
  for (int n=0;n<NN;n++) if (n<len){
    float e_ = __expf(l[n]-m);
    ssum += e_; num += e_*l[n];
  }
  float sc = (ssum > 0.0f) ? (num/ssum) : 0.0f;
  out[b*VO + v] = sc + acc_a;
}

extern "C" void kernel_launch(void* const* d_in, const int* in_sizes, int n_in,
                              void* d_out, int out_size, void* d_ws, size_t ws_size,
                              hipStream_t stream){
  const int*   items  = (const int*)d_in[0];
  const float* A      = (const float*)d_in[1];
  const int*   mask   = (const int*)d_in[2];
  const float* emb    = (const float*)d_in[3];
  const float* w_ih   = (const float*)d_in[4];
  const float* w_hh   = (const float*)d_in[5];
  const float* b_ih   = (const float*)d_in[6];
  const float* b_hh   = (const float*)d_in[7];
  const float* b_iah  = (const float*)d_in[8];
  const float* b_oah  = (const float*)d_in[9];
  const float* W_ein  = (const float*)d_in[10];
  const float* b_ein  = (const float*)d_in[11];
  const float* W_eout = (const float*)d_in[12];
  const float* b_eout = (const float*)d_in[13];
  const float* W_one  = (const float*)d_in[14];
  const float* b_one  = (const float*)d_in[15];
  const float* W_two  = (const float*)d_in[16];
  const float* b_two  = (const float*)d_in[17];
  const float* w_three= (const float*)d_in[18];
  const float* W_tr   = (const float*)d_in[19];
  const float* b_tr   = (const float*)d_in[20];
  const float* W_t    = (const float*)d_in[21];
  float* ws  = (float*)d_ws;
  float* out = (float*)d_out;

  k_embed<<<400,256,0,stream>>>(items,emb,ws);
  for (int s=0;s<2;s++){
    k_einout<<<100,256,0,stream>>>(W_ein,b_ein,W_eout,b_eout,ws);
    k_cell  <<<112,256,0,stream>>>(A,b_iah,b_oah,w_ih,w_hh,b_ih,b_hh,ws);
  }
  k_attn<<<16,128,0,stream>>>(mask,W_one,b_one,W_two,b_two,w_three,W_tr,b_tr,ws);
  k_qt  <<<100,256,0,stream>>>(mask,W_t,ws);
  k_scores<<<dim3(157,16),256,0,stream>>>(emb,ws,out);
}

// Round 4
// 443.351 us; speedup vs baseline: 2.1054x; 2.1054x over previous
//
#include <hip/hip_runtime.h>

#define BB 16
#define NN 50
#define HH 128
#define VV 40000
#define VO 39999

typedef unsigned short u16;
typedef unsigned int u32;
typedef __attribute__((ext_vector_type(8))) short short8;
typedef __attribute__((ext_vector_type(4))) float f32x4;

// ---- workspace layout (float offsets) ---- high-water 559,120 f32 = 2.24 MB
#define OFF_HID    0          // 800*128
#define OFF_EIN    102400     // 800*128 ; reused as q2all after GRU
#define OFF_Q2     102400
#define OFF_EOUT   204800     // 800*128 ; reused after GRU:
#define OFF_Q1     204800     //   16*128
#define OFF_HT     206848     //   16*128
#define OFF_ALG    208896     //   800
#define OFF_QTBF   307200     // 16*64*128 bf16 = 65536 f32 slots (ends 372736)
#define OFF_AF     409600     // 16*128
#define OFF_LEN    411648     // 16 ints
#define OFF_WIHT   411664     // 256*384 (k-major w_ih^T)  ends 509968
#define OFF_WHHT   509968     // 128*384 (k-major w_hh^T)  ends 559120

__device__ __forceinline__ float sigm(float x){ return 1.0f/(1.0f+__expf(-x)); }
__device__ __forceinline__ u16 f2b(float f){
  union { float f; u32 i; } c; c.f = f;
  u32 u = c.i;
  return (u16)((u + 0x7fffu + ((u >> 16) & 1u)) >> 16);
}

// ---- transpose w_ih / w_hh to k-major once ----
__global__ void k_prepT(const float* __restrict__ w_ih, const float* __restrict__ w_hh,
                        float* __restrict__ ws){
  int idx = blockIdx.x*256 + threadIdx.x;
  if (idx < 98304){ int k = idx/384, j = idx - k*384; ws[OFF_WIHT+idx] = w_ih[j*256+k]; }
  else if (idx < 147456){ int t2 = idx-98304; int k = t2/384, j = t2 - k*384; ws[OFF_WHHT+t2] = w_hh[j*128+k]; }
}

// ---- hidden = emb[items]  (800*128) ----
__global__ void k_embed(const int* __restrict__ items, const float* __restrict__ emb,
                        float* __restrict__ ws){
  int idx = blockIdx.x*256 + threadIdx.x;   // covers 102400
  int r = idx >> 7, h = idx & 127;
  ws[OFF_HID + idx] = emb[items[r]*128 + h];
}

// ---- ein/eout = hidden @ W^T + b   (8 rows per block) ----
__global__ void k_einout(const float* __restrict__ W_ein, const float* __restrict__ b_ein,
                         const float* __restrict__ W_eout, const float* __restrict__ b_eout,
                         float* __restrict__ ws){
  __shared__ float hl[1024];
  int t = threadIdx.x;
  int r0 = blockIdx.x * 8;
  for (int i=0;i<4;i++) hl[t + i*256] = ws[OFF_HID + r0*128 + t + i*256];
  __syncthreads();
  int h = t & 127;
  const float* W = (t<128) ? W_ein : W_eout;
  float bias = ((t<128)? b_ein : b_eout)[h];
  float* dst = (t<128) ? (ws+OFF_EIN) : (ws+OFF_EOUT);
  float wr[128];
  const float4* wp = (const float4*)(W + h*128);
  #pragma unroll
  for (int q=0;q<32;q++){
    float4 w = wp[q];
    wr[q*4]=w.x; wr[q*4+1]=w.y; wr[q*4+2]=w.z; wr[q*4+3]=w.w;
  }
  for (int rr=0; rr<8; rr++){
    float acc = bias;
    const float* hr = hl + rr*128;
    #pragma unroll 8
    for (int k=0;k<128;k++) acc += hr[k] * wr[k];
    dst[(r0+rr)*128 + h] = acc;
  }
}

// ---- fused GNN cell, block = 384 threads ----
__global__ void __launch_bounds__(384) k_cell(const float* __restrict__ A,
                       const float* __restrict__ b_iah, const float* __restrict__ b_oah,
                       const float* __restrict__ b_ih, const float* __restrict__ b_hh,
                       float* __restrict__ ws){
  __shared__ float hl[1024];     // 8 rows x 128
  __shared__ float inp[2048];    // 8 rows x 256
  __shared__ float gil[3072];    // 8 rows x 384
  __shared__ float ghl[3072];
  int t = threadIdx.x;
  int b = blockIdx.x / 7;
  int n0 = (blockIdx.x - b*7) * 8;
  // stage hidden rows
  for (int o=t; o<1024; o+=384){
    int rr=o>>7, h=o&127, row=n0+rr;
    hl[o] = (row<NN) ? ws[OFF_HID + (b*NN+row)*128 + h] : 0.0f;
  }
  // phase 1: inp[rr*256 + c8]: c8<128 -> input_in (ein), else input_out (eout)
  for (int o=t; o<2048; o+=384){
    int rr = o>>8, c8 = o&255;
    int half = (c8 < 128) ? 1 : 0;
    int c = c8 & 127;
    int row = n0 + rr;
    float acc = 0.0f;
    if (row < NN){
      acc = half ? b_iah[c] : b_oah[c];
      const float* Ar = A + (size_t)(b*NN+row)*(2*NN) + (half?0:NN);
      const float* src = ws + (half?OFF_EIN:OFF_EOUT) + b*NN*128 + c;
      for (int m=0;m<NN;m++) acc += Ar[m] * src[m*128];
    }
    inp[o] = acc;
  }
  __syncthreads();
  // phase 2: thread = output column j (0..383); coalesced wT reads, LDS broadcast
  {
    int j = t;
    float gi[8], gh[8];
    float bi = b_ih[j], bh = b_hh[j];
    #pragma unroll
    for (int r=0;r<8;r++){ gi[r]=bi; gh[r]=bh; }
    const float* wti = ws + OFF_WIHT;   // [k][384]
    const float* wth = ws + OFF_WHHT;   // [k][384]
    for (int k=0;k<256;k+=4){
      float w0 = wti[(k+0)*384+j], w1 = wti[(k+1)*384+j];
      float w2 = wti[(k+2)*384+j], w3_ = wti[(k+3)*384+j];
      #pragma unroll
      for (int r=0;r<8;r++){
        float4 iv = *(const float4*)(inp + r*256 + k);
        gi[r] += iv.x*w0 + iv.y*w1 + iv.z*w2 + iv.w*w3_;
      }
    }
    for (int k=0;k<128;k+=4){
      float w0 = wth[(k+0)*384+j], w1 = wth[(k+1)*384+j];
      float w2 = wth[(k+2)*384+j], w3_ = wth[(k+3)*384+j];
      #pragma unroll
      for (int r=0;r<8;r++){
        float4 hv = *(const float4*)(hl + r*128 + k);
        gh[r] += hv.x*w0 + hv.y*w1 + hv.z*w2 + hv.w*w3_;
      }
    }
    #pragma unroll
    for (int r=0;r<8;r++){ gil[r*384+j]=gi[r]; ghl[r*384+j]=gh[r]; }
  }
  __syncthreads();
  // phase 3: gates + update
  for (int o=t; o<1024; o+=384){
    int rr=o>>7, h=o&127, row=n0+rr;
    if (row<NN){
      float ir_=gil[rr*384+h], ii=gil[rr*384+128+h], inw=gil[rr*384+256+h];
      float hr_=ghl[rr*384+h], hi=ghl[rr*384+128+h], hn=ghl[rr*384+256+h];
      float rg=sigm(ir_+hr_), ig=sigm(ii+hi), ng=tanhf(inw+rg*hn);
      float hv=hl[o];
      ws[OFF_HID + (b*NN+row)*128 + h] = ng + ig*(hv-ng);
    }
  }
}

// ---- q2all[r][t] = b_two[t] + hid[r]·W_two[t]  (800x128) ----
__global__ void k_q2all(const float* __restrict__ W_two, const float* __restrict__ b_two,
                        float* __restrict__ ws){
  __shared__ float hlb[1024];
  int tid = threadIdx.x;
  int t = tid & 127, g = tid >> 7;
  int r0 = blockIdx.x*8;
  for (int i=0;i<4;i++) hlb[tid+i*256] = ws[OFF_HID + r0*128 + tid + i*256];
  __syncthreads();
  float wr[128];
  const float4* wp = (const float4*)(W_two + t*128);
  #pragma unroll
  for (int q=0;q<32;q++){ float4 w=wp[q]; wr[q*4]=w.x; wr[q*4+1]=w.y; wr[q*4+2]=w.z; wr[q*4+3]=w.w; }
  float bt = b_two[t];
  for (int i=0;i<4;i++){
    int rr = g*4 + i;
    float acc = bt;
    const float* hr = hlb + rr*128;
    #pragma unroll 8
    for (int k=0;k<128;k++) acc += hr[k]*wr[k];
    ws[OFF_Q2 + (r0+rr)*128 + t] = acc;
  }
}

// ---- q1[b][t], ht[b][t], len[b] ----
__global__ void k_q1len(const int* __restrict__ mask, const float* __restrict__ W_one,
                        const float* __restrict__ b_one, float* __restrict__ ws){
  __shared__ float htl[128];
  int t = threadIdx.x, b = blockIdx.x;
  int len=0;
  for (int n=0;n<NN;n++) len += mask[b*NN+n];
  if(len<1)len=1; if(len>NN)len=NN;
  const float* hid = ws + OFF_HID + b*NN*128;
  float ht = hid[(len-1)*128 + t];
  ws[OFF_HT + b*128 + t] = ht;
  htl[t] = ht;
  __syncthreads();
  const float4* wp = (const float4*)(W_one + t*128);
  float q1 = b_one[t];
  for (int q=0;q<32;q++){
    float4 w = wp[q];
    q1 += htl[q*4]*w.x + htl[q*4+1]*w.y + htl[q*4+2]*w.z + htl[q*4+3]*w.w;
  }
  ws[OFF_Q1 + b*128 + t] = q1;
  if (t==0) ((int*)(ws+OFF_LEN))[b] = len;
}

// ---- alpha_logits[r] = sum_t w3[t]*sigmoid(q1[b][t]+q2[r][t]) ; one wave per row ----
__global__ void k_alpha(const float* __restrict__ w_three, float* __restrict__ ws){
  int lane = threadIdx.x & 63, w = threadIdx.x >> 6;
  int r = blockIdx.x*4 + w;   // 0..799
  int b = r / NN;
  float s;
  {
    float q1a = ws[OFF_Q1 + b*128 + lane];
    float q2a = ws[OFF_Q2 + r*128 + lane];
    s = w_three[lane] * sigm(q1a+q2a);
    float q1b = ws[OFF_Q1 + b*128 + 64 + lane];
    float q2b = ws[OFF_Q2 + r*128 + 64 + lane];
    s += w_three[64+lane] * sigm(q1b+q2b);
  }
  for (int off=32; off; off>>=1) s += __shfl_xor(s, off);
  if (lane==0) ws[OFF_ALG + r] = s;
}

// ---- softmax over alpha; a = sum alpha*hid; af = [a,ht] @ W_tr^T + b_tr ----
__global__ void k_soft_a(const float* __restrict__ W_tr, const float* __restrict__ b_tr,
                         float* __restrict__ ws){
  __shared__ float al[128], htl[128], alpha[NN];
  int t = threadIdx.x, b = blockIdx.x;
  int len = ((const int*)(ws+OFF_LEN))[b];
  if (t==0){
    float mx=-1e30f;
    for (int n=0;n<len;n++) mx = fmaxf(mx, ws[OFF_ALG + b*NN + n]);
    float ssum=0.f;
    for (int n=0;n<len;n++){ float e=__expf(ws[OFF_ALG+b*NN+n]-mx); alpha[n]=e; ssum+=e; }
    float inv = (ssum>0.f) ? 1.f/ssum : 0.f;
    for (int n=0;n<len;n++) alpha[n]*=inv;
  }
  __syncthreads();
  const float* hid = ws + OFF_HID + b*NN*128;
  float a = 0.f;
  for (int n=0;n<len;n++) a += alpha[n]*hid[n*128+t];
  al[t] = a;
  htl[t] = ws[OFF_HT + b*128 + t];
  __syncthreads();
  const float4* wp = (const float4*)(W_tr + t*256);
  float af = b_tr[t];
  for (int q=0;q<32;q++){
    float4 w = wp[q];
    af += al[q*4]*w.x + al[q*4+1]*w.y + al[q*4+2]*w.z + al[q*4+3]*w.w;
  }
  for (int q=32;q<64;q++){
    float4 w = wp[q]; int k=(q-32)*4;
    af += htl[k]*w.x + htl[k+1]*w.y + htl[k+2]*w.z + htl[k+3]*w.w;
  }
  ws[OFF_AF + b*128 + t] = af;
}

// ---- qt_bf16[b][n(64 pad)][k] = bf16( (hid*mask) @ W_t^T ) ----
__global__ void k_qt(const int* __restrict__ mask, const float* __restrict__ W_t,
                     float* __restrict__ ws){
  u16* qtbf = (u16*)(ws + OFF_QTBF);
  if (blockIdx.x >= 100){
    // zero pad rows 50..63: 16b*14n*128k = 28672 u16 = 3584 uint4
    int p = (blockIdx.x-100)*256 + threadIdx.x;
    int b = p/224, rem = p - b*224, n = NN + rem/16, k8 = rem & 15;
    uint4 z = make_uint4(0,0,0,0);
    *(uint4*)(qtbf + ((b*64+n)*128 + k8*8)) = z;
    return;
  }
  __shared__ float hlb[1024];
  int t = threadIdx.x;
  int r0 = blockIdx.x*8;
  for (int i=0;i<4;i++) hlb[t+i*256] = ws[OFF_HID + r0*128 + t + i*256];
  __syncthreads();
  int h = t & 127, g = t >> 7;
  float wr[128];
  const float4* wp = (const float4*)(W_t + h*128);
  #pragma unroll
  for (int q=0;q<32;q++){ float4 w=wp[q]; wr[q*4]=w.x; wr[q*4+1]=w.y; wr[q*4+2]=w.z; wr[q*4+3]=w.w; }
  for (int i=0;i<4;i++){
    int rr = g*4 + i;
    int r = r0 + rr;
    float acc = 0.0f;
    if (mask[r]){
      const float* hr = hlb + rr*128;
      #pragma unroll 8
      for (int k=0;k<128;k++) acc += hr[k]*wr[k];
    }
    int b = r/NN, n = r - b*NN;
    qtbf[(b*64+n)*128 + h] = f2b(acc);
  }
}

// ---- MFMA scores: per wave 16 v; per b: logits D[64 n][16 v], softmax, + f32 a·emb ----
__global__ void __launch_bounds__(256) k_scores(const float* __restrict__ emb,
                                                const float* __restrict__ ws,
                                                float* __restrict__ out){
  int tid = threadIdx.x;
  int lane = tid & 63, wave = tid >> 6;
  int quad = lane >> 4, vlo = lane & 15;
  int v = blockIdx.x*64 + wave*16 + vlo;
  int vc = (v < VO) ? v : (VO-1);
  const float* erow = emb + (size_t)(vc+1)*128;
  // load emb row chunk per lane: k = kc*32 + quad*8 + j ; keep f32, pack bf16 frags
  float ef[32];
  short8 bfr[4];
  #pragma unroll
  for (int kc=0;kc<4;kc++){
    const float4* p = (const float4*)(erow + kc*32 + quad*8);
    float4 x = p[0], y = p[1];
    ef[kc*8+0]=x.x; ef[kc*8+1]=x.y; ef[kc*8+2]=x.z; ef[kc*8+3]=x.w;
    ef[kc*8+4]=y.x; ef[kc*8+5]=y.y; ef[kc*8+6]=y.z; ef[kc*8+7]=y.w;
    union { short8 s; u32 w[4]; } u;
    u.w[0] = (u32)f2b(x.x) | ((u32)f2b(x.y)<<16);
    u.w[1] = (u32)f2b(x.z) | ((u32)f2b(x.w)<<16);
    u.w[2] = (u32)f2b(y.x) | ((u32)f2b(y.y)<<16);
    u.w[3] = (u32)f2b(y.z) | ((u32)f2b(y.w)<<16);
    bfr[kc] = u.s;
  }
  const u16* qtbf = (const u16*)(ws + OFF_QTBF);
  const int* slen = (const int*)(ws + OFF_LEN);
  int nbase = quad*4;
  for (int b=0;b<16;b++){
    int len = slen[b]; if(len<1)len=1; if(len>NN)len=NN;
    const u16* qb = qtbf + b*64*128;
    f32x4 acc0={0.f,0.f,0.f,0.f}, acc1=acc0, acc2=acc0, acc3=acc0;
    #pragma unroll
    for (int kc=0;kc<4;kc++){
      int ko = kc*32 + quad*8;
      short8 a0 = *(const short8*)(qb + ( 0+vlo)*128 + ko);
      short8 a1 = *(const short8*)(qb + (16+vlo)*128 + ko);
      short8 a2 = *(const short8*)(qb + (32+vlo)*128 + ko);
      short8 a3 = *(const short8*)(qb + (48+vlo)*128 + ko);
      acc0 = __builtin_amdgcn_mfma_f32_16x16x32_bf16(a0, bfr[kc], acc0, 0,0,0);
      acc1 = __builtin_amdgcn_mfma_f32_16x16x32_bf16(a1, bfr[kc], acc1, 0,0,0);
      acc2 = __builtin_amdgcn_mfma_f32_16x16x32_bf16(a2, bfr[kc], acc2, 0,0,0);
      acc3 = __builtin_amdgcn_mfma_f32_16x16x32_bf16(a3, bfr[kc], acc3, 0,0,0);
    }
    // lane holds l at n = tile*16 + quad*4 + r, col v
    float mx = -1e30f;
    #pragma unroll
    for (int r=0;r<4;r++){
      if (nbase+r      < len) mx = fmaxf(mx, acc0[r]);
      if (nbase+r+16   < len) mx = fmaxf(mx, acc1[r]);
      if (nbase+r+32   < len) mx = fmaxf(mx, acc2[r]);
      if (nbase+r+48   < len) mx = fmaxf(mx, acc3[r]);
    }
    mx = fmaxf(mx, __shfl_xor(mx,16));
    mx = fmaxf(mx, __shfl_xor(mx,32));
    float ss=0.f, nm=0.f;
    #pragma unroll
    for (int r=0;r<4;r++){
      { int n=nbase+r;    if(n<len){ float e=__expf(acc0[r]-mx); ss+=e; nm+=e*acc0[r]; } }
      { int n=nbase+r+16; if(n<len){ float e=__expf(acc1[r]-mx); ss+=e; nm+=e*acc1[r]; } }
      { int n=nbase+r+32; if(n<len){ float e=__expf(acc2[r]-mx); ss+=e; nm+=e*acc2[r]; } }
      { int n=nbase+r+48; if(n<len){ float e=__expf(acc3[r]-mx); ss+=e; nm+=e*acc3[r]; } }
    }
    // f32 a·emb partial on this lane's k subset
    const float* ab = ws + OFF_AF + b*128;
    float pa = 0.f;
    #pragma unroll
    for (int kc=0;kc<4;kc++){
      const float4* ap = (const float4*)(ab + kc*32 + quad*8);
      float4 a0 = ap[0], a1 = ap[1];
      pa += a0.x*ef[kc*8+0] + a0.y*ef[kc*8+1] + a0.z*ef[kc*8+2] + a0.w*ef[kc*8+3]
          + a1.x*ef[kc*8+4] + a1.y*ef[kc*8+5] + a1.z*ef[kc*8+6] + a1.w*ef[kc*8+7];
    }
    ss += __shfl_xor(ss,16); ss += __shfl_xor(ss,32);
    nm += __shfl_xor(nm,16); nm += __shfl_xor(nm,32);
    pa += __shfl_xor(pa,16); pa += __shfl_xor(pa,32);
    float score = ((ss>0.f)?(nm/ss):0.f) + pa;
    if (quad==0 && v < VO) out[(size_t)b*VO + v] = score;
  }
}

extern "C" void kernel_launch(void* const* d_in, const int* in_sizes, int n_in,
                              void* d_out, int out_size, void* d_ws, size_t ws_size,
                              hipStream_t stream){
  const int*   items  = (const int*)d_in[0];
  const float* A      = (const float*)d_in[1];
  const int*   mask   = (const int*)d_in[2];
  const float* emb    = (const float*)d_in[3];
  const float* w_ih   = (const float*)d_in[4];
  const float* w_hh   = (const float*)d_in[5];
  const float* b_ih   = (const float*)d_in[6];
  const float* b_hh   = (const float*)d_in[7];
  const float* b_iah  = (const float*)d_in[8];
  const float* b_oah  = (const float*)d_in[9];
  const float* W_ein  = (const float*)d_in[10];
  const float* b_ein  = (const float*)d_in[11];
  const float* W_eout = (const float*)d_in[12];
  const float* b_eout = (const float*)d_in[13];
  const float* W_one  = (const float*)d_in[14];
  const float* b_one  = (const float*)d_in[15];
  const float* W_two  = (const float*)d_in[16];
  const float* b_two  = (const float*)d_in[17];
  const float* w_three= (const float*)d_in[18];
  const float* W_tr   = (const float*)d_in[19];
  const float* b_tr   = (const float*)d_in[20];
  const float* W_t    = (const float*)d_in[21];
  float* ws  = (float*)d_ws;
  float* out = (float*)d_out;

  k_prepT<<<576,256,0,stream>>>(w_ih,w_hh,ws);
  k_embed<<<400,256,0,stream>>>(items,emb,ws);
  for (int s=0;s<2;s++){
    k_einout<<<100,256,0,stream>>>(W_ein,b_ein,W_eout,b_eout,ws);
    k_cell  <<<112,384,0,stream>>>(A,b_iah,b_oah,b_ih,b_hh,ws);
  }
  k_q2all <<<100,256,0,stream>>>(W_two,b_two,ws);
  k_q1len <<<16,128,0,stream>>>(mask,W_one,b_one,ws);
  k_alpha <<<200,256,0,stream>>>(w_three,ws);
  k_soft_a<<<16,128,0,stream>>>(W_tr,b_tr,ws);
  k_qt    <<<114,256,0,stream>>>(mask,W_t,ws);
  k_scores<<<625,256,0,stream>>>(emb,ws,out);
}

// Round 5
// 332.366 us; speedup vs baseline: 2.8084x; 1.3339x over previous
//
#include <hip/hip_runtime.h>

#define BB 16
#define NN 50
#define HH 128
#define VV 40000
#define VO 39999

typedef unsigned short u16;
typedef unsigned int u32;
typedef __attribute__((ext_vector_type(8))) short short8;
typedef __attribute__((ext_vector_type(4))) float f32x4;

// ---- workspace layout (float offsets) ---- high-water 673,808 f32 = 2.70 MB
#define OFF_HID    0          // 800*128
#define OFF_EIN    102400     // 800*128 ; reused as q2 after GRU
#define OFF_Q2     102400
#define OFF_EOUT   204800     // 800*128 ; reused after GRU:
#define OFF_Q1     204800     //   16*128
#define OFF_HT     206848     //   16*128
#define OFF_QTBF   307200     // 16*64*128 bf16 (rows 50=af_hi, 51=af_lo, 52..63=0)
#define OFF_LEN    411648     // 16 ints
#define OFF_WIHT   411664     // 256*384 k-major
#define OFF_WHHT   509968     // 128*384
#define OFF_WEINT  559120     // 128*128
#define OFF_WEOUTT 575504
#define OFF_WTWOT  591888
#define OFF_WTT    608272
#define OFF_WONET  624656
#define OFF_WTRT   641040     // 256*128  -> ends 673808

__device__ __forceinline__ float sigm(float x){ return 1.0f/(1.0f+__expf(-x)); }
__device__ __forceinline__ float b2f(u16 u){
  union { u32 i; float f; } c; c.i = ((u32)u) << 16; return c.f;
}
__device__ __forceinline__ u16 f2b(float f){
  union { float f; u32 i; } c; c.f = f;
  u32 u = c.i;
  return (u16)((u + 0x7fffu + ((u >> 16) & 1u)) >> 16);
}

// ---- merged: embedding gather + transpose all weights to k-major ----
__global__ void k_pre(const int* __restrict__ items, const float* __restrict__ emb,
                      const float* __restrict__ w_ih, const float* __restrict__ w_hh,
                      const float* __restrict__ W_ein, const float* __restrict__ W_eout,
                      const float* __restrict__ W_two, const float* __restrict__ W_t,
                      const float* __restrict__ W_one, const float* __restrict__ W_tr,
                      float* __restrict__ ws){
  int idx = blockIdx.x*256 + threadIdx.x;     // grid covers exactly 364544
  if (idx < 102400){
    int r = idx >> 7, h = idx & 127;
    ws[OFF_HID + idx] = emb[items[r]*128 + h];
  } else if (idx < 200704){
    int i = idx-102400; int k=i/384, j=i-k*384;
    ws[OFF_WIHT + i] = w_ih[j*256 + k];
  } else if (idx < 249856){
    int i = idx-200704; int k=i/384, j=i-k*384;
    ws[OFF_WHHT + i] = w_hh[j*128 + k];
  } else if (idx < 266240){
    int i = idx-249856; int k=i>>7, h=i&127;
    ws[OFF_WEINT + i] = W_ein[h*128 + k];
  } else if (idx < 282624){
    int i = idx-266240; int k=i>>7, h=i&127;
    ws[OFF_WEOUTT + i] = W_eout[h*128 + k];
  } else if (idx < 299008){
    int i = idx-282624; int k=i>>7, h=i&127;
    ws[OFF_WTWOT + i] = W_two[h*128 + k];
  } else if (idx < 315392){
    int i = idx-299008; int k=i>>7, h=i&127;
    ws[OFF_WTT + i] = W_t[h*128 + k];
  } else if (idx < 331776){
    int i = idx-315392; int k=i>>7, h=i&127;
    ws[OFF_WONET + i] = W_one[h*128 + k];
  } else if (idx < 364544){
    int i = idx-331776; int k=i>>7, h=i&127;   // k<256
    ws[OFF_WTRT + i] = W_tr[h*256 + k];
  }
}

// ---- ein/eout = hidden @ W^T + b  (8 rows/block; k-chunked, no reg arrays >8) ----
__global__ void __launch_bounds__(256) k_einout(const float* __restrict__ b_ein,
                         const float* __restrict__ b_eout, float* __restrict__ ws){
  __shared__ float hl[1024];
  int t = threadIdx.x;
  int r0 = blockIdx.x * 8;
  for (int i=0;i<4;i++) hl[t + i*256] = ws[OFF_HID + r0*128 + t + i*256];
  __syncthreads();
  int h = t & 127;
  const float* wT = ws + ((t<128) ? OFF_WEINT : OFF_WEOUTT);
  float bias = ((t<128)? b_ein : b_eout)[h];
  float acc[8];
  #pragma unroll
  for (int r=0;r<8;r++) acc[r] = bias;
  for (int k4=0;k4<32;k4++){
    int k = k4*4;
    float w0 = wT[(k+0)*128+h], w1 = wT[(k+1)*128+h];
    float w2 = wT[(k+2)*128+h], w3 = wT[(k+3)*128+h];
    #pragma unroll
    for (int rr=0;rr<8;rr++){
      float4 hv = *(const float4*)(hl + rr*128 + k);
      acc[rr] += hv.x*w0 + hv.y*w1 + hv.z*w2 + hv.w*w3;
    }
  }
  float* dst = ws + ((t<128) ? OFF_EIN : OFF_EOUT);
  #pragma unroll
  for (int rr=0;rr<8;rr++) dst[(r0+rr)*128 + h] = acc[rr];
}

// ---- fused GNN cell, block = 384 threads (verified R4) ----
__global__ void __launch_bounds__(384) k_cell(const float* __restrict__ A,
                       const float* __restrict__ b_iah, const float* __restrict__ b_oah,
                       const float* __restrict__ b_ih, const float* __restrict__ b_hh,
                       float* __restrict__ ws){
  __shared__ float hl[1024];
  __shared__ float inp[2048];
  __shared__ float gil[3072];
  __shared__ float ghl[3072];
  int t = threadIdx.x;
  int b = blockIdx.x / 7;
  int n0 = (blockIdx.x - b*7) * 8;
  for (int o=t; o<1024; o+=384){
    int rr=o>>7, h=o&127, row=n0+rr;
    hl[o] = (row<NN) ? ws[OFF_HID + (b*NN+row)*128 + h] : 0.0f;
  }
  for (int o=t; o<2048; o+=384){
    int rr = o>>8, c8 = o&255;
    int half = (c8 < 128) ? 1 : 0;
    int c = c8 & 127;
    int row = n0 + rr;
    float acc = 0.0f;
    if (row < NN){
      acc = half ? b_iah[c] : b_oah[c];
      const float* Ar = A + (size_t)(b*NN+row)*(2*NN) + (half?0:NN);
      const float* src = ws + (half?OFF_EIN:OFF_EOUT) + b*NN*128 + c;
      for (int m=0;m<NN;m++) acc += Ar[m] * src[m*128];
    }
    inp[o] = acc;
  }
  __syncthreads();
  {
    int j = t;
    float gi[8], gh[8];
    float bi = b_ih[j], bh = b_hh[j];
    #pragma unroll
    for (int r=0;r<8;r++){ gi[r]=bi; gh[r]=bh; }
    const float* wti = ws + OFF_WIHT;
    const float* wth = ws + OFF_WHHT;
    for (int k=0;k<256;k+=4){
      float w0 = wti[(k+0)*384+j], w1 = wti[(k+1)*384+j];
      float w2 = wti[(k+2)*384+j], w3_ = wti[(k+3)*384+j];
      #pragma unroll
      for (int r=0;r<8;r++){
        float4 iv = *(const float4*)(inp + r*256 + k);
        gi[r] += iv.x*w0 + iv.y*w1 + iv.z*w2 + iv.w*w3_;
      }
    }
    for (int k=0;k<128;k+=4){
      float w0 = wth[(k+0)*384+j], w1 = wth[(k+1)*384+j];
      float w2 = wth[(k+2)*384+j], w3_ = wth[(k+3)*384+j];
      #pragma unroll
      for (int r=0;r<8;r++){
        float4 hv = *(const float4*)(hl + r*128 + k);
        gh[r] += hv.x*w0 + hv.y*w1 + hv.z*w2 + hv.w*w3_;
      }
    }
    #pragma unroll
    for (int r=0;r<8;r++){ gil[r*384+j]=gi[r]; ghl[r*384+j]=gh[r]; }
  }
  __syncthreads();
  for (int o=t; o<1024; o+=384){
    int rr=o>>7, h=o&127, row=n0+rr;
    if (row<NN){
      float ir_=gil[rr*384+h], ii=gil[rr*384+128+h], inw=gil[rr*384+256+h];
      float hr_=ghl[rr*384+h], hi=ghl[rr*384+128+h], hn=ghl[rr*384+256+h];
      float rg=sigm(ir_+hr_), ig=sigm(ii+hi), ng=tanhf(inw+rg*hn);
      float hv=hl[o];
      ws[OFF_HID + (b*NN+row)*128 + h] = ng + ig*(hv-ng);
    }
  }
}

// ---- merged post-GRU: q2all (blk 0..99) | qt->bf16 (blk 100..199) | pad (200..247) | q1/ht/len (248..263) ----
__global__ void __launch_bounds__(256) k_post(const int* __restrict__ mask,
                      const float* __restrict__ b_two, const float* __restrict__ b_one,
                      float* __restrict__ ws){
  int bx = blockIdx.x, t = threadIdx.x;
  u16* qtbf = (u16*)(ws + OFF_QTBF);
  if (bx < 200){
    bool isq2 = bx < 100;
    int r0 = (isq2 ? bx : bx-100) * 8;
    __shared__ float hl[1024];
    for (int i=0;i<4;i++) hl[t+i*256] = ws[OFF_HID + r0*128 + t + i*256];
    __syncthreads();
    int h = t & 127, g = t >> 7;
    const float* wT = ws + (isq2 ? OFF_WTWOT : OFF_WTT);
    float binit = isq2 ? b_two[h] : 0.0f;
    float acc[4];
    #pragma unroll
    for (int r=0;r<4;r++) acc[r] = binit;
    for (int k4=0;k4<32;k4++){
      int k = k4*4;
      float w0 = wT[(k+0)*128+h], w1 = wT[(k+1)*128+h];
      float w2 = wT[(k+2)*128+h], w3 = wT[(k+3)*128+h];
      #pragma unroll
      for (int r=0;r<4;r++){
        float4 hv = *(const float4*)(hl + (g*4+r)*128 + k);
        acc[r] += hv.x*w0 + hv.y*w1 + hv.z*w2 + hv.w*w3;
      }
    }
    #pragma unroll
    for (int r=0;r<4;r++){
      int row = r0 + g*4 + r;
      if (isq2) ws[OFF_Q2 + row*128 + h] = acc[r];
      else {
        float val = mask[row] ? acc[r] : 0.0f;
        int b = row/NN, n = row - b*NN;
        qtbf[(b*64+n)*128 + h] = f2b(val);
      }
    }
  } else if (bx < 248){
    // zero rows 52..63 of each b: 16*12*128 u16 = 12288 u32
    int idx = (bx-200)*256 + t;
    int b = idx/768, rem = idx - b*768, n = 52 + rem/64, w = rem & 63;
    ((u32*)qtbf)[(b*64+n)*64 + w] = 0u;
  } else {
    __shared__ float htl[128];
    int b = bx - 248;
    int len = 0;
    if (t < 128){
      for (int n=0;n<NN;n++) len += mask[b*NN+n];
      if (len<1) len=1; if (len>NN) len=NN;
      float ht = ws[OFF_HID + (b*NN + len-1)*128 + t];
      ws[OFF_HT + b*128 + t] = ht;
      htl[t] = ht;
    }
    __syncthreads();
    if (t < 128){
      const float* w1T = ws + OFF_WONET;
      float q1 = b_one[t];
      for (int k=0;k<128;k++) q1 += htl[k] * w1T[k*128 + t];
      ws[OFF_Q1 + b*128 + t] = q1;
      if (t==0) ((int*)(ws+OFF_LEN))[b] = len;
    }
  }
}

// ---- attention: alpha logits + softmax + a + af; write af as bf16 hi/lo qt rows 50/51 ----
__global__ void k_attn2(const float* __restrict__ w_three, const float* __restrict__ b_tr,
                        float* __restrict__ ws){
  __shared__ float q2l[NN*129];
  __shared__ float q1l[128], w3l[128], htl[128], al[128], alg[64];
  int t = threadIdx.x;   // 128
  int b = blockIdx.x;
  for (int o=t;o<NN*128;o+=128){ int n=o>>7, h=o&127; q2l[n*129+h] = ws[OFF_Q2 + b*NN*128 + o]; }
  q1l[t] = ws[OFF_Q1 + b*128 + t];
  w3l[t] = w_three[t];
  htl[t] = ws[OFF_HT + b*128 + t];
  int len = ((const int*)(ws+OFF_LEN))[b];
  __syncthreads();
  if (t < len){
    float s = 0.0f;
    const float* qr = q2l + t*129;
    for (int h=0;h<128;h++) s += w3l[h]*sigm(q1l[h]+qr[h]);
    alg[t] = s;
  }
  __syncthreads();
  if (t == 0){
    float mx = -1e30f;
    for (int n=0;n<len;n++) mx = fmaxf(mx, alg[n]);
    float ssum = 0.0f;
    for (int n=0;n<len;n++){ float e=__expf(alg[n]-mx); alg[n]=e; ssum+=e; }
    float inv = (ssum>0.0f)?1.0f/ssum:0.0f;
    for (int n=0;n<len;n++) alg[n]*=inv;
  }
  __syncthreads();
  const float* hid = ws + OFF_HID + b*NN*128;
  float a = 0.0f;
  for (int n=0;n<len;n++) a += alg[n]*hid[n*128+t];
  al[t] = a;
  __syncthreads();
  const float* wtr = ws + OFF_WTRT;
  float af = b_tr[t];
  for (int k=0;k<128;k++) af += al[k]  * wtr[k*128 + t];
  for (int k=0;k<128;k++) af += htl[k] * wtr[(128+k)*128 + t];
  u16 hi = f2b(af);
  u16 lo = f2b(af - b2f(hi));
  u16* qtbf = (u16*)(ws + OFF_QTBF);
  qtbf[(b*64+50)*128 + t] = hi;
  qtbf[(b*64+51)*128 + t] = lo;
}

// ---- MFMA scores: wave = 16 v, 4 b; af folded in as rows 50/51 (quad0 regs 2,3 of acc3) ----
__global__ void __launch_bounds__(256) k_scores(const float* __restrict__ emb,
                                                const float* __restrict__ ws,
                                                float* __restrict__ out){
  int tid = threadIdx.x;
  int lane = tid & 63, wave = tid >> 6;
  int quad = lane >> 4, vlo = lane & 15;
  int v = blockIdx.x*64 + wave*16 + vlo;
  int vc = (v < VO) ? v : (VO-1);
  const float* erow = emb + (size_t)(vc+1)*128;
  short8 bfr[4];
  #pragma unroll
  for (int kc=0;kc<4;kc++){
    const float4* p = (const float4*)(erow + kc*32 + quad*8);
    float4 x = p[0], y = p[1];
    union { short8 s; u32 w[4]; } u;
    u.w[0] = (u32)f2b(x.x) | ((u32)f2b(x.y)<<16);
    u.w[1] = (u32)f2b(x.z) | ((u32)f2b(x.w)<<16);
    u.w[2] = (u32)f2b(y.x) | ((u32)f2b(y.y)<<16);
    u.w[3] = (u32)f2b(y.z) | ((u32)f2b(y.w)<<16);
    bfr[kc] = u.s;
  }
  const u16* qtbf = (const u16*)(ws + OFF_QTBF);
  const int* slen = (const int*)(ws + OFF_LEN);
  int b0 = blockIdx.y*4;
  for (int bi=0;bi<4;bi++){
    int b = b0 + bi;
    int len = slen[b];
    const u16* qb = qtbf + b*64*128;
    f32x4 acc0={0.f,0.f,0.f,0.f}, acc1=acc0, acc2=acc0, acc3=acc0;
    #pragma unroll
    for (int kc=0;kc<4;kc++){
      int ko = kc*32 + quad*8;
      short8 a0 = *(const short8*)(qb + ( 0+vlo)*128 + ko);
      short8 a1 = *(const short8*)(qb + (16+vlo)*128 + ko);
      short8 a2 = *(const short8*)(qb + (32+vlo)*128 + ko);
      short8 a3 = *(const short8*)(qb + (48+vlo)*128 + ko);
      acc0 = __builtin_amdgcn_mfma_f32_16x16x32_bf16(a0, bfr[kc], acc0, 0,0,0);
      acc1 = __builtin_amdgcn_mfma_f32_16x16x32_bf16(a1, bfr[kc], acc1, 0,0,0);
      acc2 = __builtin_amdgcn_mfma_f32_16x16x32_bf16(a2, bfr[kc], acc2, 0,0,0);
      acc3 = __builtin_amdgcn_mfma_f32_16x16x32_bf16(a3, bfr[kc], acc3, 0,0,0);
    }
    // lane: n = tile*16 + quad*4 + r, col v=vlo. No max-subtract (|l| is O(1..8)).
    int nb = quad*4;
    float ss=0.f, nm=0.f;
    #pragma unroll
    for (int r=0;r<4;r++){
      { int n=nb+r;    if(n<len){ float e=__expf(acc0[r]); ss+=e; nm+=e*acc0[r]; } }
      { int n=nb+r+16; if(n<len){ float e=__expf(acc1[r]); ss+=e; nm+=e*acc1[r]; } }
      { int n=nb+r+32; if(n<len){ float e=__expf(acc2[r]); ss+=e; nm+=e*acc2[r]; } }
      { int n=nb+r+48; if(n<len){ float e=__expf(acc3[r]); ss+=e; nm+=e*acc3[r]; } }
    }
    ss += __shfl_xor(ss,16); ss += __shfl_xor(ss,32);
    nm += __shfl_xor(nm,16); nm += __shfl_xor(nm,32);
    if (quad==0 && v < VO){
      float pa = acc3[2] + acc3[3];   // n=50 (af_hi) + n=51 (af_lo)
      out[(size_t)b*VO + v] = nm/ss + pa;
    }
  }
}

extern "C" void kernel_launch(void* const* d_in, const int* in_sizes, int n_in,
                              void* d_out, int out_size, void* d_ws, size_t ws_size,
                              hipStream_t stream){
  const int*   items  = (const int*)d_in[0];
  const float* A      = (const float*)d_in[1];
  const int*   mask   = (const int*)d_in[2];
  const float* emb    = (const float*)d_in[3];
  const float* w_ih   = (const float*)d_in[4];
  const float* w_hh   = (const float*)d_in[5];
  const float* b_ih   = (const float*)d_in[6];
  const float* b_hh   = (const float*)d_in[7];
  const float* b_iah  = (const float*)d_in[8];
  const float* b_oah  = (const float*)d_in[9];
  const float* W_ein  = (const float*)d_in[10];
  const float* b_ein  = (const float*)d_in[11];
  const float* W_eout = (const float*)d_in[12];
  const float* b_eout = (const float*)d_in[13];
  const float* W_one  = (const float*)d_in[14];
  const float* b_one  = (const float*)d_in[15];
  const float* W_two  = (const float*)d_in[16];
  const float* b_two  = (const float*)d_in[17];
  const float* w_three= (const float*)d_in[18];
  const float* W_tr   = (const float*)d_in[19];
  const float* b_tr   = (const float*)d_in[20];
  const float* W_t    = (const float*)d_in[21];
  float* ws  = (float*)d_ws;
  float* out = (float*)d_out;

  k_pre<<<1424,256,0,stream>>>(items,emb,w_ih,w_hh,W_ein,W_eout,W_two,W_t,W_one,W_tr,ws);
  for (int s=0;s<2;s++){
    k_einout<<<100,256,0,stream>>>(b_ein,b_eout,ws);
    k_cell  <<<112,384,0,stream>>>(A,b_iah,b_oah,b_ih,b_hh,ws);
  }
  k_post <<<264,256,0,stream>>>(mask,b_two,b_one,ws);
  k_attn2<<<16,128,0,stream>>>(w_three,b_tr,ws);
  k_scores<<<dim3(625,4),256,0,stream>>>(emb,ws,out);
}

// Round 7
// 271.110 us; speedup vs baseline: 3.4430x; 1.2259x over previous
//
#include <hip/hip_runtime.h>

#define BB 16
#define NN 50
#define HH 128
#define VV 40000
#define VO 39999

typedef unsigned short u16;
typedef unsigned int u32;
typedef __attribute__((ext_vector_type(8))) short short8;
typedef __attribute__((ext_vector_type(4))) float f32x4;

// ---- workspace layout (float offsets) ---- high-water 673,808 f32 = 2.70 MB
#define OFF_HID    0          // 800*128
#define OFF_EIN    102400     // 800*128 ; reused as q2 after GRU
#define OFF_Q2     102400
#define OFF_EOUT   204800     // 800*128 ; reused after GRU:
#define OFF_Q1     204800     //   16*128
#define OFF_HT     206848     //   16*128
#define OFF_QTBF   307200     // qt fragments: per b: 4tile x 4kc x 512 u16 = 16 KB
#define OFF_LEN    411648     // 16 ints
#define OFF_WIHT   411664     // 256*384 k-major
#define OFF_WHHT   509968     // 128*384
#define OFF_WEINT  559120     // 128*128
#define OFF_WEOUTT 575504
#define OFF_WTWOT  591888
#define OFF_WTT    608272
#define OFF_WONET  624656
#define OFF_WTRT   641040     // 256*128  -> ends 673808

__device__ __forceinline__ float sigm(float x){ return 1.0f/(1.0f+__expf(-x)); }
__device__ __forceinline__ float b2f(u16 u){
  union { u32 i; float f; } c; c.i = ((u32)u) << 16; return c.f;
}
__device__ __forceinline__ u16 f2b(float f){
  union { float f; u32 i; } c; c.f = f;
  u32 u = c.i;
  return (u16)((u + 0x7fffu + ((u >> 16) & 1u)) >> 16);
}
// u16 index into qt fragment store for element (b, n, k):
// A-operand frag: lane=(quad,vlo) holds A[m=vlo][k=quad*8+j] per kc chunk, tile = n>>4
__device__ __forceinline__ int frag_idx(int b, int n, int k){
  int tile = n>>4, vlo = n&15, kc = k>>5, quad = (k>>3)&3, j = k&7;
  return (((b*4+tile)*4+kc)<<9) + ((quad<<4)+vlo)*8 + j;
}

// ---- merged: embedding gather + transpose all weights to k-major ----
__global__ void k_pre(const int* __restrict__ items, const float* __restrict__ emb,
                      const float* __restrict__ w_ih, const float* __restrict__ w_hh,
                      const float* __restrict__ W_ein, const float* __restrict__ W_eout,
                      const float* __restrict__ W_two, const float* __restrict__ W_t,
                      const float* __restrict__ W_one, const float* __restrict__ W_tr,
                      float* __restrict__ ws){
  int idx = blockIdx.x*256 + threadIdx.x;     // grid covers exactly 364544
  if (idx < 102400){
    int r = idx >> 7, h = idx & 127;
    ws[OFF_HID + idx] = emb[items[r]*128 + h];
  } else if (idx < 200704){
    int i = idx-102400; int k=i/384, j=i-k*384;
    ws[OFF_WIHT + i] = w_ih[j*256 + k];
  } else if (idx < 249856){
    int i = idx-200704; int k=i/384, j=i-k*384;
    ws[OFF_WHHT + i] = w_hh[j*128 + k];
  } else if (idx < 266240){
    int i = idx-249856; int k=i>>7, h=i&127;
    ws[OFF_WEINT + i] = W_ein[h*128 + k];
  } else if (idx < 282624){
    int i = idx-266240; int k=i>>7, h=i&127;
    ws[OFF_WEOUTT + i] = W_eout[h*128 + k];
  } else if (idx < 299008){
    int i = idx-282624; int k=i>>7, h=i&127;
    ws[OFF_WTWOT + i] = W_two[h*128 + k];
  } else if (idx < 315392){
    int i = idx-299008; int k=i>>7, h=i&127;
    ws[OFF_WTT + i] = W_t[h*128 + k];
  } else if (idx < 331776){
    int i = idx-315392; int k=i>>7, h=i&127;
    ws[OFF_WONET + i] = W_one[h*128 + k];
  } else if (idx < 364544){
    int i = idx-331776; int k=i>>7, h=i&127;   // k<256
    ws[OFF_WTRT + i] = W_tr[h*256 + k];
  }
}

// ---- ein/eout = hidden @ W^T + b  (8 rows/block) ----
__global__ void __launch_bounds__(256) k_einout(const float* __restrict__ b_ein,
                         const float* __restrict__ b_eout, float* __restrict__ ws){
  __shared__ float hl[1024];
  int t = threadIdx.x;
  int r0 = blockIdx.x * 8;
  for (int i=0;i<4;i++) hl[t + i*256] = ws[OFF_HID + r0*128 + t + i*256];
  __syncthreads();
  int h = t & 127;
  const float* wT = ws + ((t<128) ? OFF_WEINT : OFF_WEOUTT);
  float bias = ((t<128)? b_ein : b_eout)[h];
  float acc[8];
  #pragma unroll
  for (int r=0;r<8;r++) acc[r] = bias;
  for (int k4=0;k4<32;k4++){
    int k = k4*4;
    float w0 = wT[(k+0)*128+h], w1 = wT[(k+1)*128+h];
    float w2 = wT[(k+2)*128+h], w3 = wT[(k+3)*128+h];
    #pragma unroll
    for (int rr=0;rr<8;rr++){
      float4 hv = *(const float4*)(hl + rr*128 + k);
      acc[rr] += hv.x*w0 + hv.y*w1 + hv.z*w2 + hv.w*w3;
    }
  }
  float* dst = ws + ((t<128) ? OFF_EIN : OFF_EOUT);
  #pragma unroll
  for (int rr=0;rr<8;rr++) dst[(r0+rr)*128 + h] = acc[rr];
}

// ---- fused GNN cell, block = 384 threads (verified R4/R5) ----
__global__ void __launch_bounds__(384) k_cell(const float* __restrict__ A,
                       const float* __restrict__ b_iah, const float* __restrict__ b_oah,
                       const float* __restrict__ b_ih, const float* __restrict__ b_hh,
                       float* __restrict__ ws){
  __shared__ float hl[1024];
  __shared__ float inp[2048];
  __shared__ float gil[3072];
  __shared__ float ghl[3072];
  int t = threadIdx.x;
  int b = blockIdx.x / 7;
  int n0 = (blockIdx.x - b*7) * 8;
  for (int o=t; o<1024; o+=384){
    int rr=o>>7, h=o&127, row=n0+rr;
    hl[o] = (row<NN) ? ws[OFF_HID + (b*NN+row)*128 + h] : 0.0f;
  }
  for (int o=t; o<2048; o+=384){
    int rr = o>>8, c8 = o&255;
    int half = (c8 < 128) ? 1 : 0;
    int c = c8 & 127;
    int row = n0 + rr;
    float acc = 0.0f;
    if (row < NN){
      acc = half ? b_iah[c] : b_oah[c];
      const float* Ar = A + (size_t)(b*NN+row)*(2*NN) + (half?0:NN);
      const float* src = ws + (half?OFF_EIN:OFF_EOUT) + b*NN*128 + c;
      for (int m=0;m<NN;m++) acc += Ar[m] * src[m*128];
    }
    inp[o] = acc;
  }
  __syncthreads();
  {
    int j = t;
    float gi[8], gh[8];
    float bi = b_ih[j], bh = b_hh[j];
    #pragma unroll
    for (int r=0;r<8;r++){ gi[r]=bi; gh[r]=bh; }
    const float* wti = ws + OFF_WIHT;
    const float* wth = ws + OFF_WHHT;
    for (int k=0;k<256;k+=4){
      float w0 = wti[(k+0)*384+j], w1 = wti[(k+1)*384+j];
      float w2 = wti[(k+2)*384+j], w3_ = wti[(k+3)*384+j];
      #pragma unroll
      for (int r=0;r<8;r++){
        float4 iv = *(const float4*)(inp + r*256 + k);
        gi[r] += iv.x*w0 + iv.y*w1 + iv.z*w2 + iv.w*w3_;
      }
    }
    for (int k=0;k<128;k+=4){
      float w0 = wth[(k+0)*384+j], w1 = wth[(k+1)*384+j];
      float w2 = wth[(k+2)*384+j], w3_ = wth[(k+3)*384+j];
      #pragma unroll
      for (int r=0;r<8;r++){
        float4 hv = *(const float4*)(hl + r*128 + k);
        gh[r] += hv.x*w0 + hv.y*w1 + hv.z*w2 + hv.w*w3_;
      }
    }
    #pragma unroll
    for (int r=0;r<8;r++){ gil[r*384+j]=gi[r]; ghl[r*384+j]=gh[r]; }
  }
  __syncthreads();
  for (int o=t; o<1024; o+=384){
    int rr=o>>7, h=o&127, row=n0+rr;
    if (row<NN){
      float ir_=gil[rr*384+h], ii=gil[rr*384+128+h], inw=gil[rr*384+256+h];
      float hr_=ghl[rr*384+h], hi=ghl[rr*384+128+h], hn=ghl[rr*384+256+h];
      float rg=sigm(ir_+hr_), ig=sigm(ii+hi), ng=tanhf(inw+rg*hn);
      float hv=hl[o];
      ws[OFF_HID + (b*NN+row)*128 + h] = ng + ig*(hv-ng);
    }
  }
}

// ---- merged post-GRU: q2 (0..99) | qt->frags (100..199) | pad frags (200..247) | q1/ht/len (248..263) ----
__global__ void __launch_bounds__(256) k_post(const int* __restrict__ mask,
                      const float* __restrict__ b_two, const float* __restrict__ b_one,
                      float* __restrict__ ws){
  int bx = blockIdx.x, t = threadIdx.x;
  u16* qtbf = (u16*)(ws + OFF_QTBF);
  if (bx < 200){
    bool isq2 = bx < 100;
    int r0 = (isq2 ? bx : bx-100) * 8;
    __shared__ float hl[1024];
    for (int i=0;i<4;i++) hl[t+i*256] = ws[OFF_HID + r0*128 + t + i*256];
    __syncthreads();
    int h = t & 127, g = t >> 7;
    const float* wT = ws + (isq2 ? OFF_WTWOT : OFF_WTT);
    float binit = isq2 ? b_two[h] : 0.0f;
    float acc[4];
    #pragma unroll
    for (int r=0;r<4;r++) acc[r] = binit;
    for (int k4=0;k4<32;k4++){
      int k = k4*4;
      float w0 = wT[(k+0)*128+h], w1 = wT[(k+1)*128+h];
      float w2 = wT[(k+2)*128+h], w3 = wT[(k+3)*128+h];
      #pragma unroll
      for (int r=0;r<4;r++){
        float4 hv = *(const float4*)(hl + (g*4+r)*128 + k);
        acc[r] += hv.x*w0 + hv.y*w1 + hv.z*w2 + hv.w*w3;
      }
    }
    #pragma unroll
    for (int r=0;r<4;r++){
      int row = r0 + g*4 + r;
      if (isq2) ws[OFF_Q2 + row*128 + h] = acc[r];
      else {
        float val = mask[row] ? acc[r] : 0.0f;
        int b = row/NN, n = row - b*NN;
        qtbf[frag_idx(b, n, h)] = f2b(val);
      }
    }
  } else if (bx < 248){
    // zero pad rows n=52..63 (tile 3, vlo 4..15): per b 12*4*4*8 = 1536 u16; 16 b = 24576
    int i = (bx-200)*256 + t;
    #pragma unroll
    for (int kk=0;kk<2;kk++){
      int e = i*2 + kk;
      int b = e/1536, rem = e - b*1536;
      int kc = rem/384, rem2 = rem - kc*384;
      int quad = rem2/96, vv = rem2 - quad*96;
      int vlo = 4 + vv/8, j = vv & 7;
      qtbf[(((b*4+3)*4+kc)<<9) + ((quad<<4)+vlo)*8 + j] = 0;
    }
  } else {
    __shared__ float htl[128];
    int b = bx - 248;
    if (t < 128){
      int len = 0;
      for (int n=0;n<NN;n++) len += mask[b*NN+n];
      if (len<1) len=1; if (len>NN) len=NN;
      float ht = ws[OFF_HID + (b*NN + len-1)*128 + t];
      ws[OFF_HT + b*128 + t] = ht;
      htl[t] = ht;
      if (t==0) ((int*)(ws+OFF_LEN))[b] = len;
    }
    __syncthreads();
    if (t < 128){
      const float* w1T = ws + OFF_WONET;
      float q1 = b_one[t];
      for (int k=0;k<128;k++) q1 += htl[k] * w1T[k*128 + t];
      ws[OFF_Q1 + b*128 + t] = q1;
    }
  }
}

// ---- attention: alpha logits + softmax + a + af; af -> frag rows 50/51 (bf16 hi/lo) ----
__global__ void k_attn2(const float* __restrict__ w_three, const float* __restrict__ b_tr,
                        float* __restrict__ ws){
  __shared__ float q2l[NN*129];
  __shared__ float q1l[128], w3l[128], htl[128], al[128], alg[64];
  int t = threadIdx.x;   // 128
  int b = blockIdx.x;
  for (int o=t;o<NN*128;o+=128){ int n=o>>7, h=o&127; q2l[n*129+h] = ws[OFF_Q2 + b*NN*128 + o]; }
  q1l[t] = ws[OFF_Q1 + b*128 + t];
  w3l[t] = w_three[t];
  htl[t] = ws[OFF_HT + b*128 + t];
  int len = ((const int*)(ws+OFF_LEN))[b];
  __syncthreads();
  if (t < len){
    float s = 0.0f;
    const float* qr = q2l + t*129;
    for (int h=0;h<128;h++) s += w3l[h]*sigm(q1l[h]+qr[h]);
    alg[t] = s;
  }
  __syncthreads();
  if (t == 0){
    float mx = -1e30f;
    for (int n=0;n<len;n++) mx = fmaxf(mx, alg[n]);
    float ssum = 0.0f;
    for (int n=0;n<len;n++){ float e=__expf(alg[n]-mx); alg[n]=e; ssum+=e; }
    float inv = (ssum>0.0f)?1.0f/ssum:0.0f;
    for (int n=0;n<len;n++) alg[n]*=inv;
  }
  __syncthreads();
  const float* hid = ws + OFF_HID + b*NN*128;
  float a = 0.0f;
  for (int n=0;n<len;n++) a += alg[n]*hid[n*128+t];
  al[t] = a;
  __syncthreads();
  const float* wtr = ws + OFF_WTRT;
  float af = b_tr[t];
  for (int k=0;k<128;k++) af += al[k]  * wtr[k*128 + t];
  for (int k=0;k<128;k++) af += htl[k] * wtr[(128+k)*128 + t];
  u16 hi = f2b(af);
  u16 lo = f2b(af - b2f(hi));
  u16* qtbf = (u16*)(ws + OFF_QTBF);
  qtbf[frag_idx(b, 50, t)] = hi;
  qtbf[frag_idx(b, 51, t)] = lo;
}

// ---- MFMA scores: LDS-staged fragments; wave = 16 v across 4 n-tiles; 4 b per block ----
__global__ void __launch_bounds__(256) k_scores(const float* __restrict__ emb,
                                                const float* __restrict__ ws,
                                                float* __restrict__ out){
  __shared__ u16 qlds[8192];   // 16 KB = one b's fragment block
  int tid = threadIdx.x;
  int lane = tid & 63, wave = tid >> 6;
  int quad = lane >> 4, vlo = lane & 15;
  int v = blockIdx.x*64 + wave*16 + vlo;
  int vc = (v < VO) ? v : (VO-1);
  const float* erow = emb + (size_t)(vc+1)*128;
  short8 bfr[4];
  #pragma unroll
  for (int kc=0;kc<4;kc++){
    const float4* p = (const float4*)(erow + kc*32 + quad*8);
    float4 x = p[0], y = p[1];
    union { short8 s; u32 w[4]; } u;
    u.w[0] = (u32)f2b(x.x) | ((u32)f2b(x.y)<<16);
    u.w[1] = (u32)f2b(x.z) | ((u32)f2b(x.w)<<16);
    u.w[2] = (u32)f2b(y.x) | ((u32)f2b(y.y)<<16);
    u.w[3] = (u32)f2b(y.z) | ((u32)f2b(y.w)<<16);
    bfr[kc] = u.s;
  }
  const u16* qtf = (const u16*)(ws + OFF_QTBF);
  const int* slen = (const int*)(ws + OFF_LEN);
  int b0 = blockIdx.y*4;
  for (int bi=0;bi<4;bi++){
    int b = b0 + bi;
    __syncthreads();
    {
      const uint4* src = (const uint4*)qtf + (size_t)b*1024;
      uint4* dst = (uint4*)qlds;
      #pragma unroll
      for (int r=0;r<4;r++) dst[tid + r*256] = src[tid + r*256];
    }
    __syncthreads();
    int len = slen[b];
    f32x4 acc0={0.f,0.f,0.f,0.f}, acc1=acc0, acc2=acc0, acc3=acc0;
    #pragma unroll
    for (int kc=0;kc<4;kc++){
      const u16* base = qlds + kc*512 + lane*8;   // tile stride 2048 u16
      short8 a0 = *(const short8*)(base + 0*2048);
      short8 a1 = *(const short8*)(base + 1*2048);
      short8 a2 = *(const short8*)(base + 2*2048);
      short8 a3 = *(const short8*)(base + 3*2048);
      acc0 = __builtin_amdgcn_mfma_f32_16x16x32_bf16(a0, bfr[kc], acc0, 0,0,0);
      acc1 = __builtin_amdgcn_mfma_f32_16x16x32_bf16(a1, bfr[kc], acc1, 0,0,0);
      acc2 = __builtin_amdgcn_mfma_f32_16x16x32_bf16(a2, bfr[kc], acc2, 0,0,0);
      acc3 = __builtin_amdgcn_mfma_f32_16x16x32_bf16(a3, bfr[kc], acc3, 0,0,0);
    }
    // lane: n = tile*16 + quad*4 + r, col v=vlo. No max-subtract (|l| is O(1..8)).
    int nb = quad*4;
    float ss=0.f, nm=0.f;
    #pragma unroll
    for (int r=0;r<4;r++){
      { int n=nb+r;    if(n<len){ float e=__expf(acc0[r]); ss+=e; nm+=e*acc0[r]; } }
      { int n=nb+r+16; if(n<len){ float e=__expf(acc1[r]); ss+=e; nm+=e*acc1[r]; } }
      { int n=nb+r+32; if(n<len){ float e=__expf(acc2[r]); ss+=e; nm+=e*acc2[r]; } }
      { int n=nb+r+48; if(n<len){ float e=__expf(acc3[r]); ss+=e; nm+=e*acc3[r]; } }
    }
    ss += __shfl_xor(ss,16); ss += __shfl_xor(ss,32);
    nm += __shfl_xor(nm,16); nm += __shfl_xor(nm,32);
    if (quad==0 && v < VO){
      float pa = acc3[2] + acc3[3];   // n=50 (af_hi) + n=51 (af_lo)
      out[(size_t)b*VO + v] = nm/ss + pa;
    }
  }
}

extern "C" void kernel_launch(void* const* d_in, const int* in_sizes, int n_in,
                              void* d_out, int out_size, void* d_ws, size_t ws_size,
                              hipStream_t stream){
  const int*   items  = (const int*)d_in[0];
  const float* A      = (const float*)d_in[1];
  const int*   mask   = (const int*)d_in[2];
  const float* emb    = (const float*)d_in[3];
  const float* w_ih   = (const float*)d_in[4];
  const float* w_hh   = (const float*)d_in[5];
  const float* b_ih   = (const float*)d_in[6];
  const float* b_hh   = (const float*)d_in[7];
  const float* b_iah  = (const float*)d_in[8];
  const float* b_oah  = (const float*)d_in[9];
  const float* W_ein  = (const float*)d_in[10];
  const float* b_ein  = (const float*)d_in[11];
  const float* W_eout = (const float*)d_in[12];
  const float* b_eout = (const float*)d_in[13];
  const float* W_one  = (const float*)d_in[14];
  const float* b_one  = (const float*)d_in[15];
  const float* W_two  = (const float*)d_in[16];
  const float* b_two  = (const float*)d_in[17];
  const float* w_three= (const float*)d_in[18];
  const float* W_tr   = (const float*)d_in[19];
  const float* b_tr   = (const float*)d_in[20];
  const float* W_t    = (const float*)d_in[21];
  float* ws  = (float*)d_ws;
  float* out = (float*)d_out;

  k_pre<<<1424,256,0,stream>>>(items,emb,w_ih,w_hh,W_ein,W_eout,W_two,W_t,W_one,W_tr,ws);
  for (int s=0;s<2;s++){
    k_einout<<<100,256,0,stream>>>(b_ein,b_eout,ws);
    k_cell  <<<112,384,0,stream>>>(A,b_iah,b_oah,b_ih,b_hh,ws);
  }
  k_post <<<264,256,0,stream>>>(mask,b_two,b_one,ws);
  k_attn2<<<16,128,0,stream>>>(w_three,b_tr,ws);
  k_scores<<<dim3(625,4),256,0,stream>>>(emb,ws,out);
}